// Round 4
// baseline (3686.906 us; speedup 1.0000x reference)
//
#include <hip/hip_runtime.h>
#include <hip/hip_bf16.h>

#define NUM_LABELS 64
#define ENC_DIM 256
#define CC 128
#define C2 256
#define OUT_DIM 512
#define NLAYERS 5
#define MAX_T 48
#define BATCH 8
#define T_ENC 64
#define LAB_PAD 0
#define LAB_START 5
#define LAB_STOP 6

// ---------------------------------------------------------------------------
// Kernel A: precompute E2[l] = embed[l]@w_in + b_in   (64 x 256)
//           encp[b,k] = enc[b,:,k]@w_enc + b_enc      (8 x 48 x 256)
// ---------------------------------------------------------------------------
__global__ __launch_bounds__(256) void pre_kernel(
    const float* __restrict__ enc, const float* __restrict__ embed,
    const float* __restrict__ w_in, const float* __restrict__ b_in,
    const float* __restrict__ w_enc, const float* __restrict__ b_enc,
    float* __restrict__ E2, float* __restrict__ encp)
{
    const int t = threadIdx.x;
    const int blk = blockIdx.x;
    if (blk < NUM_LABELS) {
        float acc = b_in[t];
        const float* e = embed + blk * C2;
        for (int j = 0; j < C2; ++j) acc += e[j] * w_in[j * C2 + t];
        E2[blk * C2 + t] = acc;
    } else {
        const int idx = blk - NUM_LABELS;
        const int b = idx / MAX_T;
        const int k = idx % MAX_T;
        float acc = b_enc[t];
        const float* ecol = enc + b * ENC_DIM * T_ENC + k;
        for (int c = 0; c < ENC_DIM; ++c) acc += ecol[c * T_ENC] * w_enc[c * C2 + t];
        encp[idx * C2 + t] = acc;
    }
}

// ---------------------------------------------------------------------------
// Kernel B: uniform prefix chain -> h0 (5 x 128) fp32
// ---------------------------------------------------------------------------
__global__ __launch_bounds__(256) void prefix_kernel(
    const float* __restrict__ embed, const float* __restrict__ w_in,
    const float* __restrict__ b_in,  const float* __restrict__ b_enc,
    const float* __restrict__ w1,    const float* __restrict__ b1,
    const float* __restrict__ wd,    const float* __restrict__ bd,
    const float* __restrict__ w2,    const float* __restrict__ b2,
    float* __restrict__ h0out)
{
    const int t = threadIdx.x;
    __shared__ float x[C2];
    __shared__ float r[C2];
    __shared__ float h[CC];
    __shared__ float hr[CC];

    {
        float acc = b_in[t] + b_enc[t];
        const float* e = embed + LAB_PAD * C2;
        for (int j = 0; j < C2; ++j) acc += e[j] * w_in[j * C2 + t];
        x[t] = acc;
    }
    __syncthreads();

    for (int i = 0; i < NLAYERS; ++i) {
        r[t] = fmaxf(x[t], 0.f);
        __syncthreads();
        if (t < CC) {
            float a = b1[i * CC + t];
            const float* W = w1 + (i * C2) * CC + t;
            for (int j = 0; j < C2; ++j) a += r[j] * W[j * CC];
            float hv = fmaxf(a, 0.f);
            h[t] = hv;
            h0out[i * CC + t] = hv;
        }
        __syncthreads();
        if (t < CC) {
            float a = bd[i * CC + t];
            const float* W0 = wd + ((i * 3 + 0) * CC) * CC + t;
            const float* W1 = wd + ((i * 3 + 1) * CC) * CC + t;
            const float* W2 = wd + ((i * 3 + 2) * CC) * CC + t;
            for (int c = 0; c < CC; ++c)
                a += h[c] * (W0[c * CC] + W1[c * CC] + W2[c * CC]);
            hr[t] = fmaxf(a, 0.f);
        }
        __syncthreads();
        {
            float a = b2[i * C2 + t];
            const float* W = w2 + (i * CC) * C2 + t;
            for (int c = 0; c < CC; ++c) a += hr[c] * W[c * C2];
            x[t] += a;
        }
        __syncthreads();
    }
}

// ---------------------------------------------------------------------------
// Repack fp32 [ROWS][OUT] -> float4 chunks: chunk p = jb*OUT + c holds
// W[jb*4 .. jb*4+3][c]. Wave reads 1KB contiguous per dwordx4 issue.
// ---------------------------------------------------------------------------
__global__ __launch_bounds__(256) void repack4_kernel(
    const float* __restrict__ src, float4* __restrict__ dst, int OUT)
{
    const int p = blockIdx.x * 256 + threadIdx.x;
    const int c = p % OUT;
    const int jb = p / OUT;
    const float* s = src + (size_t)jb * 4 * OUT + c;
    float4 v;
    v.x = s[0 * OUT]; v.y = s[1 * OUT]; v.z = s[2 * OUT]; v.w = s[3 * OUT];
    dst[p] = v;
}

// ---------------------------------------------------------------------------
// Kernel C: 48-step sequential decode. 512 threads, fp32, float4 weight
// chunks, float4 LDS activation reads, input-split matvecs + LDS reduction.
// ---------------------------------------------------------------------------
__global__ __launch_bounds__(512) void decode_kernel(
    const float4* __restrict__ w1c,  const float* __restrict__ b1,
    const float4* __restrict__ wdc,  const float* __restrict__ bd,
    const float4* __restrict__ w2c,  const float* __restrict__ b2,
    const float4* __restrict__ wo1c, const float* __restrict__ bo1,
    const float4* __restrict__ wo2c, const float* __restrict__ bo2,
    const float* __restrict__ E2, const float* __restrict__ encp,
    const float* __restrict__ h0g, float* __restrict__ out)
{
    const int b = blockIdx.x;
    const int t = threadIdx.x;

    __shared__ alignas(16) float ring0[3 * CC];
    __shared__ alignas(16) float ring1[5 * CC];
    __shared__ alignas(16) float ring2[9 * CC];
    __shared__ alignas(16) float ring3[17 * CC];
    __shared__ alignas(16) float ring4[33 * CC];
    __shared__ alignas(16) float h0s[NLAYERS * CC];
    __shared__ alignas(16) float xs[C2];    // residual stream
    __shared__ alignas(16) float rs[C2];    // relu(x)
    __shared__ alignas(16) float hr[CC];    // relu(conv)
    __shared__ alignas(16) float us[OUT_DIM];
    __shared__ float part[512];
    __shared__ int s_lab, s_stop;

    float* rings[NLAYERS] = { ring0, ring1, ring2, ring3, ring4 };
    const int rszc[NLAYERS] = { 3, 5, 9, 17, 33 };

    for (int idx = t; idx < NLAYERS * CC; idx += 512) h0s[idx] = h0g[idx];
    if (t == 0) { s_lab = LAB_START; s_stop = MAX_T; }
    __syncthreads();

    for (int k = 0; k < MAX_T; ++k) {
        if (t < C2) {
            float xv = E2[s_lab * C2 + t] + encp[(b * MAX_T + k) * C2 + t];
            xs[t] = xv;
            rs[t] = fmaxf(xv, 0.f);
        }
        __syncthreads();

#pragma unroll
        for (int i = 0; i < NLAYERS; ++i) {
            const int d = 1 << i;
            const int rsz = rszc[i];
            const int cslot = k % rsz;
            float* rng = rings[i];

            // ---- A: h = relu(rs @ w1 + b1). 4-way input split. ----
            {
                const int c = t & 127, g = t >> 7;      // g: 0..3, 64 inputs each
                const float4* W = w1c + (i * 64 + g * 16) * 128 + c;
                const float* rp = rs + g * 64;
                float acc = 0.f;
#pragma unroll
                for (int m = 0; m < 16; ++m) {
                    float4 w = W[m * 128];
                    float4 v = *(const float4*)(rp + m * 4);
                    acc += w.x * v.x + w.y * v.y + w.z * v.z + w.w * v.w;
                }
                part[t] = acc;
            }
            __syncthreads();
            if (t < CC) {
                float hv = fmaxf(part[t] + part[t + 128] + part[t + 256] + part[t + 384]
                                 + b1[i * CC + t], 0.f);
                rng[cslot * CC + t] = hv;
            }
            __syncthreads();

            // ---- B: dilated conv, taps k-2d, k-d, k. 4-way input split. ----
            {
                const int c = t & 127, g = t >> 7;      // 32 inputs per tap per g
                const float* cur = rng + cslot * CC;
                const float* tp1 = (k >= d)     ? rng + ((k - d) % rsz) * CC     : h0s + i * CC;
                const float* tp0 = (k >= 2 * d) ? rng + ((k - 2 * d) % rsz) * CC : h0s + i * CC;
                const float4* W0 = wdc + ((i * 3 + 0) * 32 + g * 8) * 128 + c;
                const float4* W1 = wdc + ((i * 3 + 1) * 32 + g * 8) * 128 + c;
                const float4* W2 = wdc + ((i * 3 + 2) * 32 + g * 8) * 128 + c;
                float acc = 0.f;
#pragma unroll
                for (int m = 0; m < 8; ++m) {
                    float4 wa = W0[m * 128];
                    float4 wb = W1[m * 128];
                    float4 wc = W2[m * 128];
                    float4 a0 = *(const float4*)(tp0 + g * 32 + m * 4);
                    float4 a1 = *(const float4*)(tp1 + g * 32 + m * 4);
                    float4 a2 = *(const float4*)(cur + g * 32 + m * 4);
                    acc += wa.x * a0.x + wa.y * a0.y + wa.z * a0.z + wa.w * a0.w;
                    acc += wb.x * a1.x + wb.y * a1.y + wb.z * a1.z + wb.w * a1.w;
                    acc += wc.x * a2.x + wc.y * a2.y + wc.z * a2.z + wc.w * a2.w;
                }
                part[t] = acc;
            }
            __syncthreads();
            if (t < CC) {
                hr[t] = fmaxf(part[t] + part[t + 128] + part[t + 256] + part[t + 384]
                              + bd[i * CC + t], 0.f);
            }
            __syncthreads();

            // ---- C: x += hr @ w2 + b2; refresh rs. 2-way input split. ----
            {
                const int c = t & 255, g = t >> 8;      // g: 0..1, 64 inputs each
                const float4* W = w2c + (i * 32 + g * 16) * 256 + c;
                const float* hp = hr + g * 64;
                float acc = 0.f;
#pragma unroll
                for (int m = 0; m < 16; ++m) {
                    float4 w = W[m * 256];
                    float4 v = *(const float4*)(hp + m * 4);
                    acc += w.x * v.x + w.y * v.y + w.z * v.z + w.w * v.w;
                }
                part[t] = acc;
            }
            __syncthreads();
            if (t < C2) {
                float xv = xs[t] + part[t] + part[t + 256] + b2[i * C2 + t];
                xs[t] = xv;
                rs[t] = fmaxf(xv, 0.f);
            }
            __syncthreads();
        }

        // ---- head D: u = relu(x @ wo1 + bo1), 1 output/thread (x, not relu!) ----
        {
            float acc = bo1[t];
            const float4* W = wo1c + t;
#pragma unroll 16
            for (int jb = 0; jb < 64; ++jb) {
                float4 w = W[jb * 512];
                float4 v = *(const float4*)(xs + jb * 4);
                acc += w.x * v.x + w.y * v.y + w.z * v.z + w.w * v.w;
            }
            us[t] = fmaxf(acc, 0.f);
        }
        __syncthreads();

        // ---- head E: logits = u @ wo2 + bo2, 8-way input split ----
        {
            const int c = t & 63, g = t >> 6;           // g: 0..7, 64 inputs each
            const float4* W = wo2c + (g * 16) * 64 + c;
            const float* up = us + g * 64;
            float acc = 0.f;
#pragma unroll
            for (int m = 0; m < 16; ++m) {
                float4 w = W[m * 64];
                float4 v = *(const float4*)(up + m * 4);
                acc += w.x * v.x + w.y * v.y + w.z * v.z + w.w * v.w;
            }
            part[t] = acc;
        }
        __syncthreads();
        if (t < NUM_LABELS) {
            float v = part[t] + part[t + 64] + part[t + 128] + part[t + 192]
                    + part[t + 256] + part[t + 320] + part[t + 384] + part[t + 448]
                    + bo2[t];
            out[(b * NUM_LABELS + t) * MAX_T + k] = v;
            float bv = v; int bi = t;
#pragma unroll
            for (int off = 32; off; off >>= 1) {
                float ov = __shfl_xor(bv, off);
                int oi = __shfl_xor(bi, off);
                if (ov > bv || (ov == bv && oi < bi)) { bv = ov; bi = oi; }
            }
            if (t == 0) {
                s_lab = bi;
                if (bi == LAB_STOP && s_stop == MAX_T) s_stop = k;
            }
        }
        __syncthreads();
    }

    if (t == 0) out[BATCH * NUM_LABELS * MAX_T + b] = (float)s_stop;
}

// ---------------------------------------------------------------------------
extern "C" void kernel_launch(void* const* d_in, const int* in_sizes, int n_in,
                              void* d_out, int out_size, void* d_ws, size_t ws_size,
                              hipStream_t stream) {
    const float* enc   = (const float*)d_in[0];
    const float* embed = (const float*)d_in[1];
    const float* w_in  = (const float*)d_in[2];
    const float* b_in  = (const float*)d_in[3];
    const float* w_enc = (const float*)d_in[4];
    const float* b_enc = (const float*)d_in[5];
    const float* w1    = (const float*)d_in[6];
    const float* b1    = (const float*)d_in[7];
    const float* wd    = (const float*)d_in[8];
    const float* bd    = (const float*)d_in[9];
    const float* w2    = (const float*)d_in[10];
    const float* b2    = (const float*)d_in[11];
    const float* wo1   = (const float*)d_in[12];
    const float* bo1   = (const float*)d_in[13];
    const float* wo2   = (const float*)d_in[14];
    const float* bo2   = (const float*)d_in[15];
    float* out = (float*)d_out;
    float* wsf = (float*)d_ws;

    float* E2   = wsf;                  // 16384 f32
    float* encp = wsf + 16384;          // 98304 f32
    float* h0   = wsf + 16384 + 98304;  // 640 f32
    // float4 region starts at 115328 f32 = 461312 B (16B-aligned)
    float4* w1c  = (float4*)(wsf + 115328);   // 40960 chunks
    float4* wdc  = w1c + 40960;               // 61440
    float4* w2c  = wdc + 61440;               // 40960
    float4* wo1c = w2c + 40960;               // 32768
    float4* wo2c = wo1c + 32768;              // 8192

    pre_kernel<<<NUM_LABELS + BATCH * MAX_T, 256, 0, stream>>>(
        enc, embed, w_in, b_in, w_enc, b_enc, E2, encp);
    prefix_kernel<<<1, 256, 0, stream>>>(
        embed, w_in, b_in, b_enc, w1, b1, wd, bd, w2, b2, h0);
    repack4_kernel<<<160, 256, 0, stream>>>(w1, w1c, 128);    // 1280x128
    repack4_kernel<<<240, 256, 0, stream>>>(wd, wdc, 128);    // 1920x128
    repack4_kernel<<<160, 256, 0, stream>>>(w2, w2c, 256);    // 640x256
    repack4_kernel<<<128, 256, 0, stream>>>(wo1, wo1c, 512);  // 256x512
    repack4_kernel<<<32, 256, 0, stream>>>(wo2, wo2c, 64);    // 512x64
    decode_kernel<<<BATCH, 512, 0, stream>>>(
        w1c, b1, wdc, bd, w2c, b2, wo1c, bo1, wo2c, bo2, E2, encp, h0, out);
}

// Round 7
// 3406.255 us; speedup vs baseline: 1.0824x; 1.0824x over previous
//
#include <hip/hip_runtime.h>
#include <hip/hip_bf16.h>

#define NUM_LABELS 64
#define ENC_DIM 256
#define CC 128
#define C2 256
#define OUT_DIM 512
#define NLAYERS 5
#define MAX_T 48
#define BATCH 8
#define T_ENC 64
#define LAB_PAD 0
#define LAB_START 5
#define LAB_STOP 6

__device__ __forceinline__ float dot4(float4 wv, float4 av) {
    return wv.x * av.x + wv.y * av.y + wv.z * av.z + wv.w * av.w;
}

// ---------------------------------------------------------------------------
// Kernel A: precompute E2[l] = embed[l]@w_in + b_in   (64 x 256)
//           encp[b,k] = enc[b,:,k]@w_enc + b_enc      (8 x 48 x 256)
// ---------------------------------------------------------------------------
__global__ __launch_bounds__(256) void pre_kernel(
    const float* __restrict__ enc, const float* __restrict__ embed,
    const float* __restrict__ w_in, const float* __restrict__ b_in,
    const float* __restrict__ w_enc, const float* __restrict__ b_enc,
    float* __restrict__ E2, float* __restrict__ encp)
{
    const int t = threadIdx.x;
    const int blk = blockIdx.x;
    if (blk < NUM_LABELS) {
        float acc = b_in[t];
        const float* e = embed + blk * C2;
        for (int j = 0; j < C2; ++j) acc += e[j] * w_in[j * C2 + t];
        E2[blk * C2 + t] = acc;
    } else {
        const int idx = blk - NUM_LABELS;
        const int b = idx / MAX_T;
        const int k = idx % MAX_T;
        float acc = b_enc[t];
        const float* ecol = enc + b * ENC_DIM * T_ENC + k;
        for (int c = 0; c < ENC_DIM; ++c) acc += ecol[c * T_ENC] * w_enc[c * C2 + t];
        encp[idx * C2 + t] = acc;
    }
}

// ---------------------------------------------------------------------------
// Kernel B: uniform prefix chain -> h0 (5 x 128) fp32
// ---------------------------------------------------------------------------
__global__ __launch_bounds__(256) void prefix_kernel(
    const float* __restrict__ embed, const float* __restrict__ w_in,
    const float* __restrict__ b_in,  const float* __restrict__ b_enc,
    const float* __restrict__ w1,    const float* __restrict__ b1,
    const float* __restrict__ wd,    const float* __restrict__ bd,
    const float* __restrict__ w2,    const float* __restrict__ b2,
    float* __restrict__ h0out)
{
    const int t = threadIdx.x;
    __shared__ float x[C2];
    __shared__ float r[C2];
    __shared__ float h[CC];
    __shared__ float hr[CC];

    {
        float acc = b_in[t] + b_enc[t];
        const float* e = embed + LAB_PAD * C2;
        for (int j = 0; j < C2; ++j) acc += e[j] * w_in[j * C2 + t];
        x[t] = acc;
    }
    __syncthreads();

    for (int i = 0; i < NLAYERS; ++i) {
        r[t] = fmaxf(x[t], 0.f);
        __syncthreads();
        if (t < CC) {
            float a = b1[i * CC + t];
            const float* W = w1 + (i * C2) * CC + t;
            for (int j = 0; j < C2; ++j) a += r[j] * W[j * CC];
            float hv = fmaxf(a, 0.f);
            h[t] = hv;
            h0out[i * CC + t] = hv;
        }
        __syncthreads();
        if (t < CC) {
            float a = bd[i * CC + t];
            const float* W0 = wd + ((i * 3 + 0) * CC) * CC + t;
            const float* W1 = wd + ((i * 3 + 1) * CC) * CC + t;
            const float* W2 = wd + ((i * 3 + 2) * CC) * CC + t;
            for (int c = 0; c < CC; ++c)
                a += h[c] * (W0[c * CC] + W1[c * CC] + W2[c * CC]);
            hr[t] = fmaxf(a, 0.f);
        }
        __syncthreads();
        {
            float a = b2[i * C2 + t];
            const float* W = w2 + (i * CC) * C2 + t;
            for (int c = 0; c < CC; ++c) a += hr[c] * W[c * C2];
            x[t] += a;
        }
        __syncthreads();
    }
}

// ---------------------------------------------------------------------------
// Repack kernels: issue-order-linear chunk layouts for the 1024-thread decode.
// Chunk q holds 4 consecutive input-rows for one output col, placed so the
// decode kernel's m-th load of thread t reads chunk q = m*1024 + t.
// ---------------------------------------------------------------------------
__global__ __launch_bounds__(256) void repack_w1_kernel(
    const float* __restrict__ src, float4* __restrict__ dst)  // (5,256,128)
{
    const int p = blockIdx.x * 256 + threadIdx.x;   // < 40960
    const int i = p >> 13, q = p & 8191;
    const int m = q >> 10, t = q & 1023;
    const int g = t >> 7, c = t & 127;
    const int r0 = g * 32 + m * 4;
    const float* s = src + (i * 256 + r0) * 128 + c;
    float4 v; v.x = s[0]; v.y = s[128]; v.z = s[256]; v.w = s[384];
    dst[p] = v;
}

__global__ __launch_bounds__(256) void repack_wd_kernel(
    const float* __restrict__ src, float4* __restrict__ dst)  // (5,3,128,128)
{
    const int p = blockIdx.x * 256 + threadIdx.x;   // < 61440
    const int i = p / 12288, q = p % 12288;
    const int u = q >> 10, t = q & 1023;
    const int tap = u % 3, m = u / 3;
    const int g = t >> 7, c = t & 127;
    const int r0 = g * 16 + m * 4;
    const float* s = src + ((i * 3 + tap) * 128 + r0) * 128 + c;
    float4 v; v.x = s[0]; v.y = s[128]; v.z = s[256]; v.w = s[384];
    dst[p] = v;
}

__global__ __launch_bounds__(256) void repack_w2_kernel(
    const float* __restrict__ src, float4* __restrict__ dst)  // (5,128,256)
{
    const int p = blockIdx.x * 256 + threadIdx.x;   // < 40960
    const int i = p >> 13, q = p & 8191;
    const int m = q >> 10, t = q & 1023;
    const int g = t >> 8, c = t & 255;
    const int r0 = g * 32 + m * 4;
    const float* s = src + (i * 128 + r0) * 256 + c;
    float4 v; v.x = s[0]; v.y = s[256]; v.z = s[512]; v.w = s[768];
    dst[p] = v;
}

__global__ __launch_bounds__(256) void repack_wo1_kernel(
    const float* __restrict__ src, float4* __restrict__ dst)  // (256,512)
{
    const int p = blockIdx.x * 256 + threadIdx.x;   // < 32768
    const int m = p >> 10, t = p & 1023;
    const int g = t >> 9, c = t & 511;
    const int r0 = g * 128 + m * 4;
    const float* s = src + r0 * 512 + c;
    float4 v; v.x = s[0]; v.y = s[512]; v.z = s[1024]; v.w = s[1536];
    dst[p] = v;
}

__global__ __launch_bounds__(256) void repack_wo2_kernel(
    const float* __restrict__ src, float4* __restrict__ dst)  // (512,64)
{
    const int p = blockIdx.x * 256 + threadIdx.x;   // < 8192
    const int m = p >> 10, t = p & 1023;
    const int g = t >> 6, c = t & 63;
    const int r0 = g * 32 + m * 4;
    const float* s = src + r0 * 64 + c;
    float4 v; v.x = s[0]; v.y = s[64]; v.z = s[128]; v.w = s[192];
    dst[p] = v;
}

// ---------------------------------------------------------------------------
// Kernel C: 48-step sequential decode. 1024 threads (16 waves), fp32,
// issue-order-linear float4 weight chunks, register-tiled loads.
// ---------------------------------------------------------------------------
__global__ __launch_bounds__(1024) void decode_kernel(
    const float4* __restrict__ w1L,  const float* __restrict__ b1,
    const float4* __restrict__ wdL,  const float* __restrict__ bd,
    const float4* __restrict__ w2L,  const float* __restrict__ b2,
    const float4* __restrict__ wo1L, const float* __restrict__ bo1,
    const float4* __restrict__ wo2L, const float* __restrict__ bo2,
    const float* __restrict__ E2, const float* __restrict__ encp,
    const float* __restrict__ h0g, float* __restrict__ out)
{
    const int b = blockIdx.x;
    const int t = threadIdx.x;

    __shared__ alignas(16) float ring0[3 * CC];
    __shared__ alignas(16) float ring1[5 * CC];
    __shared__ alignas(16) float ring2[9 * CC];
    __shared__ alignas(16) float ring3[17 * CC];
    __shared__ alignas(16) float ring4[33 * CC];
    __shared__ alignas(16) float h0s[NLAYERS * CC];
    __shared__ alignas(16) float xs[C2];
    __shared__ alignas(16) float rs[C2];
    __shared__ alignas(16) float hr[CC];
    __shared__ alignas(16) float us[OUT_DIM];
    __shared__ alignas(16) float part[1024];
    __shared__ float b1s[NLAYERS * CC];
    __shared__ float bds[NLAYERS * CC];
    __shared__ float b2s[NLAYERS * C2];
    __shared__ float bo1s[OUT_DIM];
    __shared__ float bo2s[NUM_LABELS];
    __shared__ int s_lab, s_stop;

    float* rings[NLAYERS] = { ring0, ring1, ring2, ring3, ring4 };
    const int rszc[NLAYERS] = { 3, 5, 9, 17, 33 };

    // LDS staging — grid-stride loops so EVERY range is fully covered.
    for (int idx = t; idx < NLAYERS * CC; idx += 1024) {
        h0s[idx] = h0g[idx]; b1s[idx] = b1[idx]; bds[idx] = bd[idx];
    }
    for (int idx = t; idx < NLAYERS * C2; idx += 1024) b2s[idx] = b2[idx];
    for (int idx = t; idx < OUT_DIM; idx += 1024) bo1s[idx] = bo1[idx];
    for (int idx = t; idx < NUM_LABELS; idx += 1024) bo2s[idx] = bo2[idx];
    if (t == 0) { s_lab = LAB_START; s_stop = MAX_T; }
    __syncthreads();

    for (int k = 0; k < MAX_T; ++k) {
        if (t < C2) {
            float xv = E2[s_lab * C2 + t] + encp[(b * MAX_T + k) * C2 + t];
            xs[t] = xv;
            rs[t] = fmaxf(xv, 0.f);
        }
        __syncthreads();

#pragma unroll
        for (int i = 0; i < NLAYERS; ++i) {
            const int d = 1 << i;
            const int rsz = rszc[i];
            const int cslot = k % rsz;
            float* rng = rings[i];

            // ---- A: h = relu(rs @ w1 + b1). 8-way input split, 8 chunks/thr ----
            {
                const int g = t >> 7;
                const float4* Wb = w1L + i * 8192 + t;
                const float4* ra = reinterpret_cast<const float4*>(rs) + g * 8;
                float4 wv[8], av[8];
#pragma unroll
                for (int m = 0; m < 8; ++m) wv[m] = Wb[m * 1024];
#pragma unroll
                for (int m = 0; m < 8; ++m) av[m] = ra[m];
                float acc = 0.f;
#pragma unroll
                for (int m = 0; m < 8; ++m) acc += dot4(wv[m], av[m]);
                part[t] = acc;
            }
            __syncthreads();
            if (t < CC) {
                float s = b1s[i * CC + t];
#pragma unroll
                for (int g2 = 0; g2 < 8; ++g2) s += part[g2 * 128 + t];
                rng[cslot * CC + t] = fmaxf(s, 0.f);
            }
            __syncthreads();

            // ---- B: dilated conv, 3 taps, 8-way input split ----
            {
                const int g = t >> 7;
                const float* cur = rng + cslot * CC;
                const float* p1 = (k >= d)     ? rng + ((k - d) % rsz) * CC     : h0s + i * CC;
                const float* p0 = (k >= 2 * d) ? rng + ((k - 2 * d) % rsz) * CC : h0s + i * CC;
                const float4* c4  = reinterpret_cast<const float4*>(cur) + g * 4;
                const float4* a14 = reinterpret_cast<const float4*>(p1) + g * 4;
                const float4* a04 = reinterpret_cast<const float4*>(p0) + g * 4;
                const float4* Wb = wdL + i * 12288 + t;
                float4 wv[12], av[12];
#pragma unroll
                for (int m = 0; m < 4; ++m) {
                    wv[m * 3 + 0] = Wb[(m * 3 + 0) * 1024];
                    wv[m * 3 + 1] = Wb[(m * 3 + 1) * 1024];
                    wv[m * 3 + 2] = Wb[(m * 3 + 2) * 1024];
                }
#pragma unroll
                for (int m = 0; m < 4; ++m) {
                    av[m * 3 + 0] = a04[m];
                    av[m * 3 + 1] = a14[m];
                    av[m * 3 + 2] = c4[m];
                }
                float acc = 0.f;
#pragma unroll
                for (int m = 0; m < 12; ++m) acc += dot4(wv[m], av[m]);
                part[t] = acc;
            }
            __syncthreads();
            if (t < CC) {
                float s = bds[i * CC + t];
#pragma unroll
                for (int g2 = 0; g2 < 8; ++g2) s += part[g2 * 128 + t];
                hr[t] = fmaxf(s, 0.f);
            }
            __syncthreads();

            // ---- C: x += hr @ w2 + b2. 4-way input split, 8 chunks/thr ----
            {
                const int g = t >> 8;
                const float4* Wb = w2L + i * 8192 + t;
                const float4* ha = reinterpret_cast<const float4*>(hr) + g * 8;
                float4 wv[8], av[8];
#pragma unroll
                for (int m = 0; m < 8; ++m) wv[m] = Wb[m * 1024];
#pragma unroll
                for (int m = 0; m < 8; ++m) av[m] = ha[m];
                float acc = 0.f;
#pragma unroll
                for (int m = 0; m < 8; ++m) acc += dot4(wv[m], av[m]);
                part[t] = acc;
            }
            __syncthreads();
            if (t < C2) {
                float s = b2s[i * C2 + t];
#pragma unroll
                for (int g2 = 0; g2 < 4; ++g2) s += part[g2 * 256 + t];
                float xv = xs[t] + s;
                xs[t] = xv;
                rs[t] = fmaxf(xv, 0.f);
            }
            __syncthreads();
        }

        // ---- D: u = relu(x @ wo1 + bo1). 2-way split, 32 chunks/thr ----
        {
            const int g = t >> 9;
            const float4* Wb = wo1L + t;
            const float4* xa = reinterpret_cast<const float4*>(xs) + g * 32;
            float acc = 0.f;
#pragma unroll 1
            for (int mb = 0; mb < 4; ++mb) {
                float4 wv[8], av[8];
#pragma unroll
                for (int m = 0; m < 8; ++m) wv[m] = Wb[(mb * 8 + m) * 1024];
#pragma unroll
                for (int m = 0; m < 8; ++m) av[m] = xa[mb * 8 + m];
#pragma unroll
                for (int m = 0; m < 8; ++m) acc += dot4(wv[m], av[m]);
            }
            part[t] = acc;
        }
        __syncthreads();
        if (t < OUT_DIM) us[t] = fmaxf(part[t] + part[t + 512] + bo1s[t], 0.f);
        __syncthreads();

        // ---- E: logits = u @ wo2 + bo2. 16-way split, 8 chunks/thr ----
        {
            const int g = t >> 6;
            const float4* Wb = wo2L + t;
            const float4* ua = reinterpret_cast<const float4*>(us) + g * 8;
            float4 wv[8], av[8];
#pragma unroll
            for (int m = 0; m < 8; ++m) wv[m] = Wb[m * 1024];
#pragma unroll
            for (int m = 0; m < 8; ++m) av[m] = ua[m];
            float acc = 0.f;
#pragma unroll
            for (int m = 0; m < 8; ++m) acc += dot4(wv[m], av[m]);
            part[t] = acc;
        }
        __syncthreads();
        if (t < NUM_LABELS) {
            float v = bo2s[t];
#pragma unroll
            for (int g2 = 0; g2 < 16; ++g2) v += part[g2 * 64 + t];
            out[(b * NUM_LABELS + t) * MAX_T + k] = v;
            float bv = v; int bi = t;
#pragma unroll
            for (int off = 32; off; off >>= 1) {
                float ov = __shfl_xor(bv, off);
                int oi = __shfl_xor(bi, off);
                if (ov > bv || (ov == bv && oi < bi)) { bv = ov; bi = oi; }
            }
            if (t == 0) {
                s_lab = bi;
                if (bi == LAB_STOP && s_stop == MAX_T) s_stop = k;
            }
        }
        __syncthreads();
    }

    if (t == 0) out[BATCH * NUM_LABELS * MAX_T + b] = (float)s_stop;
}

// ---------------------------------------------------------------------------
extern "C" void kernel_launch(void* const* d_in, const int* in_sizes, int n_in,
                              void* d_out, int out_size, void* d_ws, size_t ws_size,
                              hipStream_t stream) {
    const float* enc   = (const float*)d_in[0];
    const float* embed = (const float*)d_in[1];
    const float* w_in  = (const float*)d_in[2];
    const float* b_in  = (const float*)d_in[3];
    const float* w_enc = (const float*)d_in[4];
    const float* b_enc = (const float*)d_in[5];
    const float* w1    = (const float*)d_in[6];
    const float* b1    = (const float*)d_in[7];
    const float* wd    = (const float*)d_in[8];
    const float* bd    = (const float*)d_in[9];
    const float* w2    = (const float*)d_in[10];
    const float* b2    = (const float*)d_in[11];
    const float* wo1   = (const float*)d_in[12];
    const float* bo1   = (const float*)d_in[13];
    const float* wo2   = (const float*)d_in[14];
    const float* bo2   = (const float*)d_in[15];
    float* out = (float*)d_out;
    float* wsf = (float*)d_ws;

    float* E2   = wsf;                  // 16384 f32
    float* encp = wsf + 16384;          // 98304 f32
    float* h0   = wsf + 16384 + 98304;  // 640 f32
    // float4 region at 115328 f32 = 461312 B (16B aligned)
    float4* w1L  = (float4*)(wsf + 115328);   // 40960 chunks
    float4* wdL  = w1L + 40960;               // 61440
    float4* w2L  = wdL + 61440;               // 40960
    float4* wo1L = w2L + 40960;               // 32768
    float4* wo2L = wo1L + 32768;              // 8192

    pre_kernel<<<NUM_LABELS + BATCH * MAX_T, 256, 0, stream>>>(
        enc, embed, w_in, b_in, w_enc, b_enc, E2, encp);
    prefix_kernel<<<1, 256, 0, stream>>>(
        embed, w_in, b_in, b_enc, w1, b1, wd, bd, w2, b2, h0);
    repack_w1_kernel<<<160, 256, 0, stream>>>(w1, w1L);
    repack_wd_kernel<<<240, 256, 0, stream>>>(wd, wdL);
    repack_w2_kernel<<<160, 256, 0, stream>>>(w2, w2L);
    repack_wo1_kernel<<<128, 256, 0, stream>>>(wo1, wo1L);
    repack_wo2_kernel<<<32, 256, 0, stream>>>(wo2, wo2L);
    decode_kernel<<<BATCH, 1024, 0, stream>>>(
        w1L, b1, wdL, bd, w2L, b2, wo1L, bo1, wo2L, bo2, E2, encp, h0, out);
}